// Round 3
// baseline (2743.475 us; speedup 1.0000x reference)
//
#include <hip/hip_runtime.h>
#include <math.h>

#define TPB 256

// ---- LDS layout (float word offsets) ----
#define W0_OFF 0        // 128 rows x 84 (80 used)
#define W0_STR 84
#define W1_OFF 10752    // 128 rows x 132 (128 used)
#define W1_STR 132
#define W2_OFF 27648    // 64 rows x 132 (128 used)
#define W2_STR 132
#define B0_OFF 36096    // 128
#define B1_OFF 36224    // 128
#define B2_OFF 36352    // 64
#define Z_OFF  36416    // 4 x 84  (z = [y(64), u(16)])
#define Z_STR  84
#define HA_OFF 36752    // 4 x 128
#define HB_OFF 37264    // 4 x 128
#define H_STR  128
#define T_OFF  37776    // 4 (published t per element)
#define SM_WORDS 37780
#define SM_BYTES (SM_WORDS * 4)

__device__ __forceinline__ float4 ld4(const float* p) {
  return *reinterpret_cast<const float4*>(p);
}

// One full MLP eval. Precondition: z rows in LDS valid, barrier passed.
// Returns k value for this thread's (e = tid>>6, dim = tid&63).
__device__ __forceinline__ float eval_f(float* sm, int tid) {
  const int j  = tid & 127;   // feature for L1/L2
  const int e0 = tid >> 7;    // handles elements e0 and e0+2

  // ---- L1: h1 = tanh(W0 z + b0), fan_in = 80 ----
  {
    float a0 = sm[B0_OFF + j];
    float a1 = a0;
    const float* wr = sm + W0_OFF + j * W0_STR;
    const float* z0 = sm + Z_OFF + e0 * Z_STR;
    const float* z1 = sm + Z_OFF + (e0 + 2) * Z_STR;
#pragma unroll
    for (int i4 = 0; i4 < 20; ++i4) {
      float4 w  = ld4(wr + i4 * 4);
      float4 za = ld4(z0 + i4 * 4);
      float4 zb = ld4(z1 + i4 * 4);
      a0 = fmaf(w.x, za.x, a0); a0 = fmaf(w.y, za.y, a0);
      a0 = fmaf(w.z, za.z, a0); a0 = fmaf(w.w, za.w, a0);
      a1 = fmaf(w.x, zb.x, a1); a1 = fmaf(w.y, zb.y, a1);
      a1 = fmaf(w.z, zb.z, a1); a1 = fmaf(w.w, zb.w, a1);
    }
    sm[HA_OFF + e0 * H_STR + j]       = tanhf(a0);
    sm[HA_OFF + (e0 + 2) * H_STR + j] = tanhf(a1);
  }
  __syncthreads();

  // ---- L2: h2 = tanh(W1 h1 + b1), fan_in = 128 ----
  {
    float a0 = sm[B1_OFF + j];
    float a1 = a0;
    const float* wr = sm + W1_OFF + j * W1_STR;
    const float* z0 = sm + HA_OFF + e0 * H_STR;
    const float* z1 = sm + HA_OFF + (e0 + 2) * H_STR;
#pragma unroll
    for (int i4 = 0; i4 < 32; ++i4) {
      float4 w  = ld4(wr + i4 * 4);
      float4 za = ld4(z0 + i4 * 4);
      float4 zb = ld4(z1 + i4 * 4);
      a0 = fmaf(w.x, za.x, a0); a0 = fmaf(w.y, za.y, a0);
      a0 = fmaf(w.z, za.z, a0); a0 = fmaf(w.w, za.w, a0);
      a1 = fmaf(w.x, zb.x, a1); a1 = fmaf(w.y, zb.y, a1);
      a1 = fmaf(w.z, zb.z, a1); a1 = fmaf(w.w, zb.w, a1);
    }
    sm[HB_OFF + e0 * H_STR + j]       = tanhf(a0);
    sm[HB_OFF + (e0 + 2) * H_STR + j] = tanhf(a1);
  }
  __syncthreads();

  // ---- L3: k = W2 h2 + b2 (no tanh). Mapping matches solver threads. ----
  const int j3 = tid & 63;
  const int e3 = tid >> 6;
  float a = sm[B2_OFF + j3];
  const float* wr = sm + W2_OFF + j3 * W2_STR;
  const float* z  = sm + HB_OFF + e3 * H_STR;
#pragma unroll
  for (int i4 = 0; i4 < 32; ++i4) {
    float4 w  = ld4(wr + i4 * 4);
    float4 z4 = ld4(z + i4 * 4);
    a = fmaf(w.x, z4.x, a); a = fmaf(w.y, z4.y, a);
    a = fmaf(w.z, z4.z, a); a = fmaf(w.w, z4.w, a);
  }
  return a;
}

__global__ __launch_bounds__(TPB, 1)
void ode_solver(const float* __restrict__ x0, const float* __restrict__ u,
                const float* __restrict__ t0p, const float* __restrict__ t1p,
                const float* __restrict__ W0g, const float* __restrict__ b0g,
                const float* __restrict__ W1g, const float* __restrict__ b1g,
                const float* __restrict__ W2g, const float* __restrict__ b2g,
                float* __restrict__ out, int B)
{
  extern __shared__ float sm[];
  const int tid = threadIdx.x;
  const int blk = blockIdx.x;

  // ---- stage weights into LDS (one-time per block) ----
  for (int idx = tid; idx < 128 * 80; idx += TPB) {
    int j = idx / 80, i = idx - j * 80;
    sm[W0_OFF + j * W0_STR + i] = W0g[idx];
  }
  for (int idx = tid; idx < 128 * 128; idx += TPB) {
    int j = idx >> 7, i = idx & 127;
    sm[W1_OFF + j * W1_STR + i] = W1g[idx];
  }
  for (int idx = tid; idx < 64 * 128; idx += TPB) {
    int j = idx >> 7, i = idx & 127;
    sm[W2_OFF + j * W2_STR + i] = W2g[idx];
  }
  if (tid < 128) { sm[B0_OFF + tid] = b0g[tid]; sm[B1_OFF + tid] = b1g[tid]; }
  if (tid < 64)  { sm[B2_OFF + tid] = b2g[tid]; }
  if (tid < 64) {           // u occupies z[64..79], constant for whole solve
    int e = tid >> 4, c = tid & 15;
    sm[Z_OFF + e * Z_STR + 64 + c] = u[(blk * 4 + e) * 16 + c];
  }

  const int ce = tid >> 6;          // element 0..3 (== wave id)
  const int cd = tid & 63;          // state dim
  const int ge = blk * 4 + ce;      // global element

  float y = x0[ge * 64 + cd];
  const float t1  = *t1p;
  const float t1m = t1 - 1e-12f;    // matches XLA: f32(1.0 - 1e-12) == 1.0f
  float tcur = *t0p;
  float dt   = (float)(60.0 * (1.0 / 3600.0));
  int nst = 0;

  // DOPRI5 coefficients (f64 literals rounded to f32, as XLA does)
  constexpr float cA21 = (float)0.161;
  constexpr float cA31 = (float)-0.008480655492356989, cA32 = (float)0.335480655492357;
  constexpr float cA41 = (float)2.8971530571054935,  cA42 = (float)-6.359448489975075,  cA43 = (float)4.3622954328695815;
  constexpr float cA51 = (float)5.325864828439257,   cA52 = (float)-11.748883564062828, cA53 = (float)7.4955393428898365, cA54 = (float)-0.09249506636175525;
  constexpr float cA61 = (float)5.86145544294642,    cA62 = (float)-12.92096931784711,  cA63 = (float)8.159367898576159,  cA64 = (float)-0.071584973281401, cA65 = (float)-0.028269050394068383;
  constexpr float cB1 = (float)0.09646076681806523,  cB2 = (float)0.01, cB3 = (float)0.4798896504144996;
  constexpr float cB4 = (float)1.379008574103742,    cB5 = (float)-3.290069515436081, cB6 = (float)2.324710524099774;
  constexpr float cE1 = (float)-0.001780011052226,   cE2 = (float)-0.000816434459657, cE3 = (float)0.007880878010262;
  constexpr float cE4 = (float)-0.144711007173263,   cE5 = (float)0.582357165452555,  cE6 = (float)-0.458082105929187;
  constexpr float cE7 = (float)(-1.0 / 66.0);

  __syncthreads();

  for (int it = 0; it < 128; ++it) {
    // publish stage-1 input (z = y) and current t; safe: all z readers passed
    // eval_f's internal L1 barrier before any thread can get here.
    sm[Z_OFF + ce * Z_STR + cd] = y;
    if (cd == 0) sm[T_OFF + ce] = tcur;
    __syncthreads();
    const bool alldone = (sm[T_OFF + 0] >= t1m) && (sm[T_OFF + 1] >= t1m) &&
                         (sm[T_OFF + 2] >= t1m) && (sm[T_OFF + 3] >= t1m);
    if (alldone) break;          // uniform across block

    const bool  done = (tcur >= t1m);
    const float dt_c = fminf(dt, t1 - tcur);
    const float d    = dt_c;

    const float k1 = eval_f(sm, tid);
    float ys = y + d * (cA21 * k1);
    sm[Z_OFF + ce * Z_STR + cd] = ys;
    __syncthreads();
    const float k2 = eval_f(sm, tid);
    ys = y + d * (cA31 * k1 + cA32 * k2);
    sm[Z_OFF + ce * Z_STR + cd] = ys;
    __syncthreads();
    const float k3 = eval_f(sm, tid);
    ys = y + d * (cA41 * k1 + cA42 * k2 + cA43 * k3);
    sm[Z_OFF + ce * Z_STR + cd] = ys;
    __syncthreads();
    const float k4 = eval_f(sm, tid);
    ys = y + d * (cA51 * k1 + cA52 * k2 + cA53 * k3 + cA54 * k4);
    sm[Z_OFF + ce * Z_STR + cd] = ys;
    __syncthreads();
    const float k5 = eval_f(sm, tid);
    ys = y + d * (cA61 * k1 + cA62 * k2 + cA63 * k3 + cA64 * k4 + cA65 * k5);
    sm[Z_OFF + ce * Z_STR + cd] = ys;
    __syncthreads();
    const float k6 = eval_f(sm, tid);
    const float y5v = y + d * (cB1 * k1 + cB2 * k2 + cB3 * k3 + cB4 * k4 + cB5 * k5 + cB6 * k6);
    sm[Z_OFF + ce * Z_STR + cd] = y5v;
    __syncthreads();
    const float k7 = eval_f(sm, tid);

    const float err = d * (cE1 * k1 + cE2 * k2 + cE3 * k3 + cE4 * k4 + cE5 * k5 + cE6 * k6 + cE7 * k7);
    const float sc  = 1.4e-8f + 1.4e-8f * fmaxf(fabsf(y), fabsf(y5v));
    const float r   = err / sc;
    float s2 = r * r;
#pragma unroll
    for (int m = 1; m < 64; m <<= 1) s2 += __shfl_xor(s2, m);
    const float en = sqrtf(s2 * (1.0f / 64.0f));

    const bool accept = (en <= 1.0f);
    float fac = 0.9f * powf(fmaxf(en, 1e-16f), -0.2f);
    fac = fminf(10.0f, fmaxf(0.1f, fac));
    const bool step = accept && !done;
    if (step) { tcur = tcur + dt_c; y = y5v; }
    if (!done) dt = dt_c * fac;
    nst += done ? 0 : 1;
  }

  // ---- outputs: y (B x 64) then nsteps (B) as float ----
  out[ge * 64 + cd] = y;
  if (cd == 0) out[B * 64 + ge] = (float)nst;
}

extern "C" void kernel_launch(void* const* d_in, const int* in_sizes, int n_in,
                              void* d_out, int out_size, void* d_ws, size_t ws_size,
                              hipStream_t stream) {
  const float* x0 = (const float*)d_in[0];
  const float* u  = (const float*)d_in[1];
  const float* t0 = (const float*)d_in[2];
  const float* t1 = (const float*)d_in[3];
  const float* W0 = (const float*)d_in[4];
  const float* b0 = (const float*)d_in[5];
  const float* W1 = (const float*)d_in[6];
  const float* b1 = (const float*)d_in[7];
  const float* W2 = (const float*)d_in[8];
  const float* b2 = (const float*)d_in[9];
  float* out = (float*)d_out;

  const int B = in_sizes[0] / 64;   // 1024
  const int nblk = B / 4;           // 4 elements per block

  (void)hipFuncSetAttribute((const void*)ode_solver,
                            hipFuncAttributeMaxDynamicSharedMemorySize, SM_BYTES);
  ode_solver<<<nblk, TPB, SM_BYTES, stream>>>(x0, u, t0, t1, W0, b0, W1, b1, W2, b2, out, B);
}